// Round 10
// baseline (841.535 us; speedup 1.0000x reference)
//
#include <hip/hip_runtime.h>
#include <hip/hip_bf16.h>

typedef unsigned short u16;
typedef __attribute__((ext_vector_type(8))) short bf16x8;
typedef __attribute__((ext_vector_type(8))) unsigned short u16x8;
typedef __attribute__((ext_vector_type(4))) unsigned short u16x4;
typedef __attribute__((ext_vector_type(4))) float f32x4;

__device__ inline float b2f(u16 u) {
    union { unsigned u32; float f; } x; x.u32 = ((unsigned)u) << 16; return x.f;
}
__device__ inline u16 f2b(float f) {
    return __builtin_bit_cast(u16, __float2bfloat16(f));
}

// tanh-form GELU: v * sigmoid(1.5957691 v + 0.07135482 v^3), |err| < ~1e-3
__device__ inline float fast_gelu(float v) {
    float u = v * (1.5957691216f + 0.0713548163f * v * v);
    return v * __builtin_amdgcn_rcpf(1.0f + __expf(-u));
}

#define GLOAD_LDS16(g, l) \
    __builtin_amdgcn_global_load_lds((const __attribute__((address_space(1))) void*)(const void*)(g), \
                                     (__attribute__((address_space(3))) void*)(void*)(l), 16, 0, 0)
#define FENCE() asm volatile("" ::: "memory")

// ---------------- weight transpose f32[K][N] -> bf16 Wt[N][K] --------------
__global__ __launch_bounds__(256)
void transpose_w(const float* __restrict__ W, u16* __restrict__ Wt, int K, int N)
{
    __shared__ float t[32][33];
    int nb = blockIdx.x * 32, kb = blockIdx.y * 32;
    int tx = threadIdx.x & 31, ty = threadIdx.x >> 5;
    #pragma unroll
    for (int r = 0; r < 32; r += 8)
        t[ty + r][tx] = W[(size_t)(kb + ty + r) * N + nb + tx];
    __syncthreads();
    #pragma unroll
    for (int r = 0; r < 32; r += 8)
        Wt[(size_t)(nb + ty + r) * K + kb + tx] = f2b(t[tx][ty + r]);
}

// ---------------- bias(+mask) table: bmT[cls][h][k][q] * log2e -------------
__global__ __launch_bounds__(256)
void build_bias(const float* __restrict__ rpb, float* __restrict__ bmT)
{
    int idx = blockIdx.x * 256 + threadIdx.x;      // 4*8*64*64 = 131072
    int q = idx & 63, k = (idx >> 6) & 63, h = (idx >> 12) & 7, cls = idx >> 15;
    int qh = q >> 3, qw = q & 7, kh = k >> 3, kw = k & 7;
    float v = rpb[((qh - kh + 7) * 15 + (qw - kw + 7)) * 8 + h];
    int ch = cls >> 1, cw = cls & 1;
    int rq = (ch ? (qh < 4 ? 1 : 2) : 0) * 3 + (cw ? (qw < 4 ? 1 : 2) : 0);
    int rk = (ch ? (kh < 4 ? 1 : 2) : 0) * 3 + (cw ? (kw < 4 ? 1 : 2) : 0);
    if (rq != rk) v -= 100.f;
    bmT[idx] = v * 1.4426950408889634f;
}

// ======== unified A-stationary GEMM (K=256), fused pre/post processing =====
// MODE 0: A = LN1(x)+shift+window-partition (f32 in), epi = bf16+bias (QKV)
// MODE 1: A = LN3(LN2(x1)) (f32 in), epi = gelu->bf16 (MLP1)
// MODE 2: A = bf16 rows, epi = f32 winrev + residual (out-proj)
// A-load is 2-pass streaming (<=8 f32 temps live) -> no VGPR spill.
// MODE1 second-LN stats come algebraically from pass-1 accumulators.
template<int MODE>
__global__ __launch_bounds__(256, 2)
void areg_gemm(const void* __restrict__ Ax, const u16* __restrict__ Bt,
               const float* __restrict__ bias, void* __restrict__ out,
               const float* __restrict__ resid,
               const float* __restrict__ lg1, const float* __restrict__ lb1,
               const float* __restrict__ lg2, const float* __restrict__ lb2,
               int N, int shift)
{
    constexpr int K = 256;
    __shared__ u16 Bs[2][8][64][32];   // 64 KB
    __shared__ float biasL[1024];
    __shared__ float lnp[4][256];
    const int tid = threadIdx.x, lane = tid & 63, wv = tid >> 6;
    const int g = lane >> 4, r = lane & 15;
    const int bid = blockIdx.x;
    const int bm = (bid & 7) * 64 + (bid >> 3);    // XCD-chunked, 512 = 8*64
    const int row0 = bm * 128 + wv * 32;

    // ---- stage params to LDS
    for (int i = tid; i < N; i += 256) biasL[i] = bias[i];
    if (MODE == 0 && tid < 256) { lnp[0][tid] = lg1[tid]; lnp[1][tid] = lb1[tid]; }
    if (MODE == 1 && tid < 256) { lnp[0][tid] = lg1[tid]; lnp[1][tid] = lb1[tid];
                                  lnp[2][tid] = lg2[tid]; lnp[3][tid] = lb2[tid]; }
    __syncthreads();

#define STAGE(bn_, buf_) do { \
        _Pragma("unroll") \
        for (int it = 0; it < 8; ++it) { \
            const int S = it * 256 + wv * 64 + lane; \
            const int ks_ = S >> 8, col_ = (S >> 2) & 63, k8_ = S & 3; \
            GLOAD_LDS16(Bt + (size_t)((bn_) * 64 + col_) * K + ks_ * 32 + k8_ * 8, \
                        &Bs[buf_][0][0][0] + (size_t)(it * 256 + wv * 64) * 8); \
        } \
    } while (0)

    STAGE(0, 0);

    // ---- A fragments (loaded once; LN fused for MODE 0/1, 2-pass streaming)
    bf16x8 af[2][8];
    if (MODE == 2) {
        const u16* A = (const u16*)Ax;
        #pragma unroll
        for (int rf = 0; rf < 2; ++rf)
            #pragma unroll
            for (int ks = 0; ks < 8; ++ks)
                af[rf][ks] = *(const bf16x8*)(A + (size_t)(row0 + rf * 16 + r) * K + ks * 32 + g * 8);
    } else {
        const float* x = (const float*)Ax;
        // channel constants for MODE1 second-LN algebra (row-independent)
        float cg = 0.f, cg2 = 0.f, cb = 0.f, cb2 = 0.f, cgb = 0.f;
        if (MODE == 1) {
            #pragma unroll
            for (int ks = 0; ks < 8; ++ks)
                #pragma unroll
                for (int e = 0; e < 8; ++e) {
                    const int c = ks * 32 + g * 8 + e;
                    const float gg = lnp[0][c], bb = lnp[1][c];
                    cg += gg; cg2 += gg * gg; cb += bb; cb2 += bb * bb; cgb += gg * bb;
                }
            cg  += __shfl_xor(cg, 16);  cg  += __shfl_xor(cg, 32);
            cg2 += __shfl_xor(cg2, 16); cg2 += __shfl_xor(cg2, 32);
            cb  += __shfl_xor(cb, 16);  cb  += __shfl_xor(cb, 32);
            cb2 += __shfl_xor(cb2, 16); cb2 += __shfl_xor(cb2, 32);
            cgb += __shfl_xor(cgb, 16); cgb += __shfl_xor(cgb, 32);
        }
        #pragma unroll
        for (int rf = 0; rf < 2; ++rf) {
            const int row = row0 + rf * 16 + r;
            size_t srow;
            if (MODE == 0) {
                int win = row >> 6, tok = row & 63;
                int bb_ = win >> 6, wib = win & 63;
                int h = (((wib >> 3) << 3) + (tok >> 3) + shift) & 63;
                int w = (((wib & 7) << 3) + (tok & 7) + shift) & 63;
                srow = (size_t)bb_ * 4096 + h * 64 + w;
            } else {
                srow = (size_t)row;
            }
            const float* xr = x + srow * 256 + g * 8;
            // ---- pass 1: streaming stats (few live regs)
            float s = 0.f, s2 = 0.f;
            float sg = 0.f, sg2x = 0.f, sg2x2 = 0.f, sgbx = 0.f;
            #pragma unroll
            for (int ks = 0; ks < 8; ++ks) {
                const f32x4 a = *(const f32x4*)(xr + ks * 32);
                const f32x4 b = *(const f32x4*)(xr + ks * 32 + 4);
                #pragma unroll
                for (int e = 0; e < 4; ++e) {
                    const float xa = a[e], xb = b[e];
                    s += xa + xb; s2 += xa * xa + xb * xb;
                    if (MODE == 1) {
                        const int c = ks * 32 + g * 8 + e;
                        const float g1 = lnp[0][c], b1 = lnp[1][c];
                        const float g2 = lnp[0][c + 4], b2 = lnp[1][c + 4];
                        sg    += g1 * xa + g2 * xb;
                        sg2x  += g1 * g1 * xa + g2 * g2 * xb;
                        sg2x2 += g1 * g1 * xa * xa + g2 * g2 * xb * xb;
                        sgbx  += g1 * b1 * xa + g2 * b2 * xb;
                    }
                }
            }
            s  += __shfl_xor(s, 16);  s  += __shfl_xor(s, 32);
            s2 += __shfl_xor(s2, 16); s2 += __shfl_xor(s2, 32);
            const float m1 = s * (1.f / 256.f);
            const float rs1 = rsqrtf(s2 * (1.f / 256.f) - m1 * m1 + 1e-5f);
            float m2 = 0.f, rs2 = 0.f;
            if (MODE == 1) {
                sg    += __shfl_xor(sg, 16);    sg    += __shfl_xor(sg, 32);
                sg2x  += __shfl_xor(sg2x, 16);  sg2x  += __shfl_xor(sg2x, 32);
                sg2x2 += __shfl_xor(sg2x2, 16); sg2x2 += __shfl_xor(sg2x2, 32);
                sgbx  += __shfl_xor(sgbx, 16);  sgbx  += __shfl_xor(sgbx, 32);
                const float sumy  = rs1 * (sg - m1 * cg) + cb;
                const float sumy2 = rs1 * rs1 * (sg2x2 - 2.f * m1 * sg2x + m1 * m1 * cg2)
                                  + 2.f * rs1 * (sgbx - m1 * cgb) + cb2;
                m2 = sumy * (1.f / 256.f);
                rs2 = rsqrtf(sumy2 * (1.f / 256.f) - m2 * m2 + 1e-6f);
            }
            // ---- pass 2: reload (L1/L2-hot), normalize, convert
            #pragma unroll
            for (int ks = 0; ks < 8; ++ks) {
                const f32x4 a = *(const f32x4*)(xr + ks * 32);
                const f32x4 b = *(const f32x4*)(xr + ks * 32 + 4);
                u16x8 o;
                #pragma unroll
                for (int e = 0; e < 8; ++e) {
                    const int c = ks * 32 + g * 8 + e;
                    const float xa = (e < 4) ? a[e & 3] : b[e & 3];
                    float y = (xa - m1) * rs1 * lnp[0][c] + lnp[1][c];
                    if (MODE == 1) y = (y - m2) * rs2 * lnp[2][c] + lnp[3][c];
                    o[e] = f2b(y);
                }
                af[rf][ks] = __builtin_bit_cast(bf16x8, o);
            }
        }
    }

    const int NB = N >> 6;
    for (int bn = 0; bn < NB; ++bn) {
        const int cur = bn & 1;
        if (bn + 1 < NB) STAGE(bn + 1, cur ^ 1);
        // stage(bn) is always the oldest unretired batch -> exact counted waits
        if (bn == 0) {
            asm volatile("s_waitcnt vmcnt(8)" ::: "memory");
        } else if (bn + 1 < NB) {
            if (MODE == 2) asm volatile("s_waitcnt vmcnt(24)" ::: "memory");
            else           asm volatile("s_waitcnt vmcnt(16)" ::: "memory");
        } else {
            if (MODE == 2) asm volatile("s_waitcnt vmcnt(16)" ::: "memory");
            else           asm volatile("s_waitcnt vmcnt(8)" ::: "memory");
        }
        __builtin_amdgcn_s_barrier();
        FENCE();
        f32x4 acc[4][2] = {};   // [cf][rf]
        #pragma unroll
        for (int ks = 0; ks < 8; ++ks) {
            bf16x8 bf[4];
            #pragma unroll
            for (int cf = 0; cf < 4; ++cf)
                bf[cf] = *(const bf16x8*)(&Bs[cur][ks][cf * 16 + r][g * 8]);
            __builtin_amdgcn_s_setprio(1);
            #pragma unroll
            for (int cf = 0; cf < 4; ++cf)
                #pragma unroll
                for (int rf = 0; rf < 2; ++rf)
                    acc[cf][rf] = __builtin_amdgcn_mfma_f32_16x16x32_bf16(bf[cf], af[rf][ks], acc[cf][rf], 0, 0, 0);
            __builtin_amdgcn_s_setprio(0);
        }
        asm volatile("s_waitcnt lgkmcnt(0)" ::: "memory");
        __builtin_amdgcn_sched_barrier(0);
        __builtin_amdgcn_s_barrier();
        FENCE();
        // ---- epilogue for this 64-col stripe (bias via LDS)
        #pragma unroll
        for (int rf = 0; rf < 2; ++rf) {
            const int row = row0 + rf * 16 + r;
            size_t orow;
            if (MODE == 2) {
                int win = row >> 6, tok = row & 63;
                int bb_ = win >> 6, wib = win & 63;
                int h = (((wib >> 3) << 3) + (tok >> 3) + shift) & 63;
                int w = (((wib & 7) << 3) + (tok & 7) + shift) & 63;
                orow = (size_t)bb_ * 4096 + h * 64 + w;
            } else {
                orow = (size_t)row;
            }
            #pragma unroll
            for (int cf = 0; cf < 4; ++cf) {
                const int colb = bn * 64 + cf * 16 + g * 4;
                const f32x4 bv = *(const f32x4*)(&biasL[colb]);
                if (MODE == 0) {
                    u16x4 o;
                    #pragma unroll
                    for (int e = 0; e < 4; ++e) o[e] = f2b(acc[cf][rf][e] + bv[e]);
                    *(u16x4*)((u16*)out + (size_t)row * N + colb) = o;
                } else if (MODE == 1) {
                    u16x4 o;
                    #pragma unroll
                    for (int e = 0; e < 4; ++e) o[e] = f2b(fast_gelu(acc[cf][rf][e] + bv[e]));
                    *(u16x4*)((u16*)out + (size_t)row * N + colb) = o;
                } else {
                    const f32x4 rv = *(const f32x4*)(resid + orow * N + colb);
                    f32x4 o;
                    #pragma unroll
                    for (int e = 0; e < 4; ++e) o[e] = rv[e] + acc[cf][rf][e] + bv[e];
                    *(f32x4*)((float*)out + orow * N + colb) = o;
                }
            }
        }
        FENCE();
    }
#undef STAGE
}

// ======== general-K 128x128 GEMM (MLP2): 4-buf, depth-2, 1 barrier/iter ====
__global__ __launch_bounds__(256)
void gemm_k4(const u16* __restrict__ A, const u16* __restrict__ Bt,
             const float* __restrict__ bias, float* __restrict__ out,
             const float* __restrict__ resid, int M, int N, int K)
{
    __shared__ u16 As[4][128][32];
    __shared__ u16 Bs[4][128][32];
    const int tid = threadIdx.x, lane = tid & 63, wv = tid >> 6;
    const int g = lane >> 4, r = lane & 15;
    const int wr = wv >> 1, wc = wv & 1;
    const int nwg = gridDim.x * gridDim.y;
    const int lid = blockIdx.y * gridDim.x + blockIdx.x;
    const int qq = nwg >> 3, r8 = nwg & 7;
    const int xcd = lid & 7, pos = lid >> 3;
    const int nid = (xcd < r8 ? xcd * (qq + 1) : r8 * (qq + 1) + (xcd - r8) * qq) + pos;
    const int bm = nid / gridDim.x, bn = nid % gridDim.x;
    f32x4 acc[4][4] = {};
    const int arow = wv * 16 + (lane >> 2);
    const int scol = (((lane & 3) ^ ((lane >> 2) & 3) ^ ((lane >> 4) & 1)) * 8);
    const u16* gA = A + (size_t)(bm * 128 + arow) * K + scol;
    const u16* gB = Bt + (size_t)(bn * 128 + arow) * K + scol;
    const int nk = K >> 5;
    const int rc = (g ^ (r & 3) ^ ((r >> 2) & 1)) * 8;

#define STAGE(t) do { \
        u16* a_ = &As[(t) & 3][0][0]; u16* b_ = &Bs[(t) & 3][0][0]; \
        GLOAD_LDS16(gA + (size_t)(t) * 32,                    a_ + wv * 512); \
        GLOAD_LDS16(gA + (size_t)(t) * 32 + (size_t)64 * K,   a_ + 2048 + wv * 512); \
        GLOAD_LDS16(gB + (size_t)(t) * 32,                    b_ + wv * 512); \
        GLOAD_LDS16(gB + (size_t)(t) * 32 + (size_t)64 * K,   b_ + 2048 + wv * 512); \
    } while (0)

    STAGE(0);
    STAGE(1);
    for (int kt = 0; kt < nk; ++kt) {
        const int cur = kt & 3;
        if (kt + 2 < nk) {
            STAGE(kt + 2);
            asm volatile("s_waitcnt vmcnt(8)" ::: "memory");
        } else if (kt + 1 < nk) {
            asm volatile("s_waitcnt vmcnt(4)" ::: "memory");
        } else {
            asm volatile("s_waitcnt vmcnt(0)" ::: "memory");
        }
        __builtin_amdgcn_s_barrier();
        FENCE();
        bf16x8 af[4], bf[4];
        #pragma unroll
        for (int i = 0; i < 4; ++i)
            af[i] = *(const bf16x8*)(&As[cur][wr * 64 + i * 16 + r][rc]);
        #pragma unroll
        for (int j = 0; j < 4; ++j)
            bf[j] = *(const bf16x8*)(&Bs[cur][wc * 64 + j * 16 + r][rc]);
        __builtin_amdgcn_s_setprio(1);
        #pragma unroll
        for (int j = 0; j < 4; ++j)
            #pragma unroll
            for (int i = 0; i < 4; ++i)
                acc[j][i] = __builtin_amdgcn_mfma_f32_16x16x32_bf16(bf[j], af[i], acc[j][i], 0, 0, 0);
        __builtin_amdgcn_s_setprio(0);
        asm volatile("s_waitcnt lgkmcnt(0)" ::: "memory");
        __builtin_amdgcn_sched_barrier(0);
    }
#undef STAGE

    #pragma unroll
    for (int i = 0; i < 4; ++i) {
        const int row = bm * 128 + wr * 64 + i * 16 + r;
        #pragma unroll
        for (int j = 0; j < 4; ++j) {
            const int colb = bn * 128 + wc * 64 + j * 16 + g * 4;
            const f32x4 bv = *(const f32x4*)(bias + colb);
            const f32x4 rv = *(const f32x4*)(resid + (size_t)row * N + colb);
            f32x4 o;
            #pragma unroll
            for (int e = 0; e < 4; ++e) o[e] = rv[e] + acc[j][i][e] + bv[e];
            *(f32x4*)(out + (size_t)row * N + colb) = o;
        }
    }
}

// ---------------- MFMA attention: one block per window, wave = 2 heads -----
template<int SHIFTED>
__global__ __launch_bounds__(256)
void attn_mfma(const u16* __restrict__ qkv, const float* __restrict__ bmT,
               u16* __restrict__ out)
{
    __shared__ u16 pbuf[4][64 * 72];
    __shared__ u16 vbuf[4][32 * 72];
    const int tid = threadIdx.x, lane = tid & 63, wv = tid >> 6;
    const int g = lane >> 4, r = lane & 15;
    const int win = blockIdx.x;
    u16* P  = pbuf[wv];
    u16* Vt = vbuf[wv];
    const u16* base = qkv + (size_t)win * 64 * 768;
    int cls = 0;
    if (SHIFTED) {
        int wib = win & 63;
        cls = (((wib >> 3) == 7) ? 2 : 0) + (((wib & 7) == 7) ? 1 : 0);
    }
    const float sc = 0.17677669529663687f * 1.4426950408889634f;

    for (int hh = 0; hh < 2; ++hh) {
        const int h = wv * 2 + hh;
        const float* bmh = bmT + ((size_t)cls * 8 + h) * 4096;
        bf16x8 kf[4], qf[4];
        #pragma unroll
        for (int i = 0; i < 4; ++i) {
            kf[i] = *(const bf16x8*)(base + (size_t)(i * 16 + r) * 768 + 256 + h * 32 + g * 8);
            qf[i] = *(const bf16x8*)(base + (size_t)(i * 16 + r) * 768 +       h * 32 + g * 8);
        }
        #pragma unroll
        for (int d0 = 0; d0 < 32; d0 += 8) {
            u16x8 vv = *(const u16x8*)(base + (size_t)lane * 768 + 512 + h * 32 + d0);
            #pragma unroll
            for (int e = 0; e < 8; ++e) Vt[(d0 + e) * 72 + lane] = vv[e];
        }
        f32x4 acc[4][4] = {};
        #pragma unroll
        for (int i = 0; i < 4; ++i)
            #pragma unroll
            for (int j = 0; j < 4; ++j)
                acc[i][j] = __builtin_amdgcn_mfma_f32_16x16x32_bf16(kf[i], qf[j], acc[i][j], 0, 0, 0);
        #pragma unroll
        for (int i = 0; i < 4; ++i) {
            const int kb = (i * 16 + g * 4) * 64;
            #pragma unroll
            for (int j = 0; j < 4; ++j) {
                const int qq = j * 16 + r;
                #pragma unroll
                for (int rr = 0; rr < 4; ++rr)
                    acc[i][j][rr] = acc[i][j][rr] * sc + bmh[kb + rr * 64 + qq];
            }
        }
        float inv_[4];
        #pragma unroll
        for (int j = 0; j < 4; ++j) {
            float m = acc[0][j][0];
            #pragma unroll
            for (int i = 0; i < 4; ++i)
                #pragma unroll
                for (int rr = 0; rr < 4; ++rr) m = fmaxf(m, acc[i][j][rr]);
            m = fmaxf(m, __shfl_xor(m, 16));
            m = fmaxf(m, __shfl_xor(m, 32));
            float s = 0.f;
            #pragma unroll
            for (int i = 0; i < 4; ++i)
                #pragma unroll
                for (int rr = 0; rr < 4; ++rr) {
                    float p = exp2f(acc[i][j][rr] - m);
                    acc[i][j][rr] = p; s += p;
                }
            s += __shfl_xor(s, 16);
            s += __shfl_xor(s, 32);
            inv_[j] = 1.f / s;
        }
        #pragma unroll
        for (int j = 0; j < 4; ++j) {
            const float iv = inv_[j];
            #pragma unroll
            for (int i = 0; i < 4; ++i) {
                u16x4 w;
                #pragma unroll
                for (int rr = 0; rr < 4; ++rr) w[rr] = f2b(acc[i][j][rr] * iv);
                *(u16x4*)(P + (j * 16 + r) * 72 + i * 16 + g * 4) = w;
            }
        }
        f32x4 o[2][4] = {};
        #pragma unroll
        for (int ks = 0; ks < 2; ++ks) {
            bf16x8 pa[4], vb[2];
            #pragma unroll
            for (int i = 0; i < 4; ++i)
                pa[i] = *(const bf16x8*)(P + (i * 16 + r) * 72 + ks * 32 + g * 8);
            #pragma unroll
            for (int j = 0; j < 2; ++j)
                vb[j] = *(const bf16x8*)(Vt + (j * 16 + r) * 72 + ks * 32 + g * 8);
            #pragma unroll
            for (int j = 0; j < 2; ++j)
                #pragma unroll
                for (int i = 0; i < 4; ++i)
                    o[j][i] = __builtin_amdgcn_mfma_f32_16x16x32_bf16(vb[j], pa[i], o[j][i], 0, 0, 0);
        }
        u16* op = out + (size_t)win * 64 * 256 + h * 32;
        #pragma unroll
        for (int i = 0; i < 4; ++i) {
            const int qrow = i * 16 + r;
            #pragma unroll
            for (int j = 0; j < 2; ++j) {
                u16x4 w;
                #pragma unroll
                for (int rr = 0; rr < 4; ++rr) w[rr] = f2b(o[j][i][rr]);
                *(u16x4*)(op + (size_t)qrow * 256 + j * 16 + g * 4) = w;
            }
        }
    }
}

// ---------------------------------------------------------------------------
extern "C" void kernel_launch(void* const* d_in, const int* in_sizes, int n_in,
                              void* d_out, int out_size, void* d_ws, size_t ws_size,
                              hipStream_t stream)
{
    (void)in_sizes; (void)n_in; (void)out_size; (void)ws_size;
    const float* x = (const float*)d_in[0];
    char* ws = (char*)d_ws;
    size_t off = 0;
    auto alloc = [&](size_t bytes) { void* p = ws + off; off += (bytes + 255) & ~(size_t)255; return p; };

    u16 *wtq[2], *wto[2], *wt1[2], *wt2[2];
    float* bmT[2];
    for (int i = 0; i < 2; ++i) {
        wtq[i] = (u16*)alloc((size_t)768 * 256 * 2);
        wto[i] = (u16*)alloc((size_t)256 * 256 * 2);
        wt1[i] = (u16*)alloc((size_t)1024 * 256 * 2);
        wt2[i] = (u16*)alloc((size_t)256 * 1024 * 2);
        bmT[i] = (float*)alloc((size_t)4 * 8 * 64 * 64 * 4);
    }
    u16*  xw  = (u16*)alloc((size_t)65536 * 256 * 2);    // attn output (windowed)
    u16*  big = (u16*)alloc((size_t)65536 * 1024 * 2);   // qkv / mlp hidden
    float* x1 = (float*)alloc((size_t)65536 * 256 * 4);  // post-attn residual stream
    float* outp = (float*)d_out;

    for (int blk = 0; blk < 2; ++blk) {
        const float* const* P = (const float* const*)(d_in + 1 + blk * 15);
        transpose_w<<<dim3(768 / 32, 256 / 32), 256, 0, stream>>>(P[2], wtq[blk], 256, 768);
        transpose_w<<<dim3(256 / 32, 256 / 32), 256, 0, stream>>>(P[5], wto[blk], 256, 256);
        transpose_w<<<dim3(1024 / 32, 256 / 32), 256, 0, stream>>>(P[11], wt1[blk], 256, 1024);
        transpose_w<<<dim3(256 / 32, 1024 / 32), 256, 0, stream>>>(P[13], wt2[blk], 1024, 256);
        build_bias<<<512, 256, 0, stream>>>(P[4], bmT[blk]);
    }

    for (int blk = 0; blk < 2; ++blk) {
        const float* const* P = (const float* const*)(d_in + 1 + blk * 15);
        const int sh = blk ? 4 : 0;
        const float* xin = blk ? outp : x;

        // QKV with fused LN1 + shift + window partition
        areg_gemm<0><<<512, 256, 0, stream>>>(xin, wtq[blk], P[3], big, nullptr,
                                              P[0], P[1], nullptr, nullptr, 768, sh);
        if (blk) attn_mfma<1><<<1024, 256, 0, stream>>>(big, bmT[blk], xw);
        else     attn_mfma<0><<<1024, 256, 0, stream>>>(big, bmT[blk], xw);
        // out-proj: winrev + residual(f32)
        areg_gemm<2><<<512, 256, 0, stream>>>(xw, wto[blk], P[6], x1, xin,
                                              nullptr, nullptr, nullptr, nullptr, 256, sh);
        // MLP1 with fused LN2(1e-5) o LN3(1e-6) + GELU
        areg_gemm<1><<<512, 256, 0, stream>>>(x1, wt1[blk], P[12], big, nullptr,
                                              P[7], P[8], P[9], P[10], 1024, 0);
        // MLP2 + residual
        gemm_k4<<<dim3(2, 512), 256, 0, stream>>>(big, wt2[blk], P[14], outp, x1, 65536, 256, 1024);
    }
}

// Round 11
// 685.669 us; speedup vs baseline: 1.2273x; 1.2273x over previous
//
#include <hip/hip_runtime.h>
#include <hip/hip_bf16.h>

typedef unsigned short u16;
typedef __attribute__((ext_vector_type(8))) short bf16x8;
typedef __attribute__((ext_vector_type(8))) unsigned short u16x8;
typedef __attribute__((ext_vector_type(4))) unsigned short u16x4;
typedef __attribute__((ext_vector_type(4))) float f32x4;

__device__ inline float b2f(u16 u) {
    union { unsigned u32; float f; } x; x.u32 = ((unsigned)u) << 16; return x.f;
}
__device__ inline u16 f2b(float f) {
    return __builtin_bit_cast(u16, __float2bfloat16(f));
}

// tanh-form GELU: v * sigmoid(1.5957691 v + 0.07135482 v^3), |err| < ~1e-3
__device__ inline float fast_gelu(float v) {
    float u = v * (1.5957691216f + 0.0713548163f * v * v);
    return v * __builtin_amdgcn_rcpf(1.0f + __expf(-u));
}

#define GLOAD_LDS16(g, l) \
    __builtin_amdgcn_global_load_lds((const __attribute__((address_space(1))) void*)(const void*)(g), \
                                     (__attribute__((address_space(3))) void*)(void*)(l), 16, 0, 0)
#define FENCE() asm volatile("" ::: "memory")

// ---------------- LN1 + shift + window partition -> bf16 ----------------
__global__ __launch_bounds__(256)
void ln_win_kernel(const float* __restrict__ x, const float* __restrict__ g,
                   const float* __restrict__ b, u16* __restrict__ xw, int shift)
{
    int wid = blockIdx.x * 4 + (threadIdx.x >> 6);
    int lane = threadIdx.x & 63;
    int win = wid >> 6, tok = wid & 63;
    int bb = win >> 6, wib = win & 63;
    int h = (((wib >> 3) << 3) + (tok >> 3) + shift) & 63;
    int w = (((wib & 7) << 3) + (tok & 7) + shift) & 63;
    size_t src = ((size_t)bb * 4096 + h * 64 + w) * 256;
    float4 v = ((const float4*)(x + src))[lane];
    float s = v.x + v.y + v.z + v.w;
    float s2 = v.x*v.x + v.y*v.y + v.z*v.z + v.w*v.w;
    for (int k = 32; k > 0; k >>= 1) { s += __shfl_xor(s, k); s2 += __shfl_xor(s2, k); }
    float mean = s * (1.f/256.f);
    float var  = s2 * (1.f/256.f) - mean*mean;
    float rs = rsqrtf(var + 1e-5f);
    int c = lane * 4;
    u16x4 o;
    o[0] = f2b((v.x - mean) * rs * g[c+0] + b[c+0]);
    o[1] = f2b((v.y - mean) * rs * g[c+1] + b[c+1]);
    o[2] = f2b((v.z - mean) * rs * g[c+2] + b[c+2]);
    o[3] = f2b((v.w - mean) * rs * g[c+3] + b[c+3]);
    *(u16x4*)(xw + (size_t)wid * 256 + c) = o;
}

// ---------------- fused LN2(1e-5) then LN3(1e-6) -> bf16 -------------------
__global__ __launch_bounds__(256)
void ln2_kernel(const float* __restrict__ xin,
                const float* __restrict__ g1, const float* __restrict__ b1,
                const float* __restrict__ g2, const float* __restrict__ b2,
                u16* __restrict__ out)
{
    int wid = blockIdx.x * 4 + (threadIdx.x >> 6);
    int lane = threadIdx.x & 63;
    float4 v = ((const float4*)(xin + (size_t)wid * 256))[lane];
    float s = v.x + v.y + v.z + v.w;
    float s2 = v.x*v.x + v.y*v.y + v.z*v.z + v.w*v.w;
    for (int k = 32; k > 0; k >>= 1) { s += __shfl_xor(s, k); s2 += __shfl_xor(s2, k); }
    float mean = s * (1.f/256.f);
    float var  = s2 * (1.f/256.f) - mean*mean;
    float rs = rsqrtf(var + 1e-5f);
    int c = lane * 4;
    float y0 = (v.x - mean) * rs * g1[c+0] + b1[c+0];
    float y1 = (v.y - mean) * rs * g1[c+1] + b1[c+1];
    float y2 = (v.z - mean) * rs * g1[c+2] + b1[c+2];
    float y3 = (v.w - mean) * rs * g1[c+3] + b1[c+3];
    float t = y0 + y1 + y2 + y3;
    float t2 = y0*y0 + y1*y1 + y2*y2 + y3*y3;
    for (int k = 32; k > 0; k >>= 1) { t += __shfl_xor(t, k); t2 += __shfl_xor(t2, k); }
    float m2 = t * (1.f/256.f);
    float v2 = t2 * (1.f/256.f) - m2*m2;
    float rs2 = rsqrtf(v2 + 1e-6f);
    u16x4 o;
    o[0] = f2b((y0 - m2) * rs2 * g2[c+0] + b2[c+0]);
    o[1] = f2b((y1 - m2) * rs2 * g2[c+1] + b2[c+1]);
    o[2] = f2b((y2 - m2) * rs2 * g2[c+2] + b2[c+2]);
    o[3] = f2b((y3 - m2) * rs2 * g2[c+3] + b2[c+3]);
    *(u16x4*)(out + (size_t)wid * 256 + c) = o;
}

// ---------------- weight transpose f32[K][N] -> bf16 Wt[N][K] --------------
__global__ __launch_bounds__(256)
void transpose_w(const float* __restrict__ W, u16* __restrict__ Wt, int K, int N)
{
    __shared__ float t[32][33];
    int nb = blockIdx.x * 32, kb = blockIdx.y * 32;
    int tx = threadIdx.x & 31, ty = threadIdx.x >> 5;
    #pragma unroll
    for (int r = 0; r < 32; r += 8)
        t[ty + r][tx] = W[(size_t)(kb + ty + r) * N + nb + tx];
    __syncthreads();
    #pragma unroll
    for (int r = 0; r < 32; r += 8)
        Wt[(size_t)(nb + ty + r) * K + kb + tx] = f2b(t[tx][ty + r]);
}

// ---------------- bias(+mask) table: bmT[cls][h][k][q] * log2e -------------
__global__ __launch_bounds__(256)
void build_bias(const float* __restrict__ rpb, float* __restrict__ bmT)
{
    int idx = blockIdx.x * 256 + threadIdx.x;      // 4*8*64*64 = 131072
    int q = idx & 63, k = (idx >> 6) & 63, h = (idx >> 12) & 7, cls = idx >> 15;
    int qh = q >> 3, qw = q & 7, kh = k >> 3, kw = k & 7;
    float v = rpb[((qh - kh + 7) * 15 + (qw - kw + 7)) * 8 + h];
    int ch = cls >> 1, cw = cls & 1;
    int rq = (ch ? (qh < 4 ? 1 : 2) : 0) * 3 + (cw ? (qw < 4 ? 1 : 2) : 0);
    int rk = (ch ? (kh < 4 ? 1 : 2) : 0) * 3 + (cw ? (kw < 4 ? 1 : 2) : 0);
    if (rq != rk) v -= 100.f;
    bmT[idx] = v * 1.4426950408889634f;
}

// ======== A-stationary GEMM (K=256): A in VGPRs, B streamed via LDS ========
// 4 waves x 32 rows = 128 rows/block; grid 512 -> 2 blocks/CU.
// T2 LDS swizzle (rule 21 both-sides): source k-octet pre-swizzled by
// swz(col) = (col&3)^((col>>2)&1); read slot rc = g ^ (r&3) ^ ((r>>2)&1).
// Store-aware vmcnt ladder: epilogue VMEM stays in flight across phases.
// EPI 0: bf16+bias (QKV); EPI 1: gelu->bf16 (MLP1); EPI 2: f32 winrev+resid.
template<int EPI>
__global__ __launch_bounds__(256, 2)
void areg_gemm(const u16* __restrict__ A, const u16* __restrict__ Bt,
               const float* __restrict__ bias, void* __restrict__ out,
               const float* __restrict__ resid, int N, int shift)
{
    constexpr int K = 256;
    __shared__ u16 Bs[2][8][64][32];   // 64 KB: [buf][ks][col][4 slots x 8 k]
    const int tid = threadIdx.x, lane = tid & 63, wv = tid >> 6;
    const int g = lane >> 4, r = lane & 15;
    const int bid = blockIdx.x;
    const int bm = (bid & 7) * 64 + (bid >> 3);    // XCD-chunked, 512 = 8*64
    const int row0 = bm * 128 + wv * 32;

    // ---- A into registers: af[rf][ks] = A[row0+rf*16+r][ks*32+g*8 ..+8]
    bf16x8 af[2][8];
    #pragma unroll
    for (int rf = 0; rf < 2; ++rf)
        #pragma unroll
        for (int ks = 0; ks < 8; ++ks)
            af[rf][ks] = *(const bf16x8*)(A + (size_t)(row0 + rf * 16 + r) * K + ks * 32 + g * 8);

    const int NB = N >> 6;
    // stage 32 KB (64 cols x 256 K) with 4 waves: 8 rounds x 1 KB/wave.
    // LDS dest linear; SOURCE k-octet swizzled so slot s holds k8 = s^swz(col).
#define STAGE(bn_, buf_) do { \
        _Pragma("unroll") \
        for (int it = 0; it < 8; ++it) { \
            const int S = it * 256 + wv * 64 + lane; \
            const int ks_ = S >> 8, col_ = (S >> 2) & 63; \
            const int k8_ = (S & 3) ^ (col_ & 3) ^ ((col_ >> 2) & 1); \
            GLOAD_LDS16(Bt + (size_t)((bn_) * 64 + col_) * K + ks_ * 32 + k8_ * 8, \
                        &Bs[buf_][0][0][0] + (size_t)(it * 256 + wv * 64) * 8); \
        } \
    } while (0)

    const int rc = (g ^ (r & 3) ^ ((r >> 2) & 1)) * 8;   // swizzled read slot

    FENCE();
    STAGE(0, 0);
    for (int bn = 0; bn < NB; ++bn) {
        const int cur = bn & 1;
        if (bn + 1 < NB) { STAGE(bn + 1, cur ^ 1); }
        // ladder: stage(bn) is the oldest unretired VMEM batch
        if (bn == 0) {
            asm volatile("s_waitcnt vmcnt(8)" ::: "memory");
        } else if (bn + 1 < NB) {
            if (EPI == 2) asm volatile("s_waitcnt vmcnt(24)" ::: "memory");
            else          asm volatile("s_waitcnt vmcnt(16)" ::: "memory");
        } else {
            if (EPI == 2) asm volatile("s_waitcnt vmcnt(16)" ::: "memory");
            else          asm volatile("s_waitcnt vmcnt(8)" ::: "memory");
        }
        __builtin_amdgcn_s_barrier();
        FENCE();
        f32x4 acc[4][2] = {};   // [cf][rf]
        #pragma unroll
        for (int ks = 0; ks < 8; ++ks) {
            bf16x8 bf[4];
            #pragma unroll
            for (int cf = 0; cf < 4; ++cf)
                bf[cf] = *(const bf16x8*)(&Bs[cur][ks][cf * 16 + r][rc]);
            __builtin_amdgcn_s_setprio(1);
            #pragma unroll
            for (int cf = 0; cf < 4; ++cf)
                #pragma unroll
                for (int rf = 0; rf < 2; ++rf)
                    acc[cf][rf] = __builtin_amdgcn_mfma_f32_16x16x32_bf16(bf[cf], af[rf][ks], acc[cf][rf], 0, 0, 0);
            __builtin_amdgcn_s_setprio(0);
        }
        asm volatile("s_waitcnt lgkmcnt(0)" ::: "memory");
        __builtin_amdgcn_sched_barrier(0);
        __builtin_amdgcn_s_barrier();
        FENCE();
        // ---- epilogue for this 64-col stripe (stores stay in flight)
        #pragma unroll
        for (int rf = 0; rf < 2; ++rf) {
            const int row = row0 + rf * 16 + r;
            size_t orow;
            if (EPI == 2) {
                int win = row >> 6, tok = row & 63;
                int bb = win >> 6, wib = win & 63;
                int h = (((wib >> 3) << 3) + (tok >> 3) + shift) & 63;
                int w = (((wib & 7) << 3) + (tok & 7) + shift) & 63;
                orow = (size_t)bb * 4096 + h * 64 + w;
            } else {
                orow = (size_t)row;
            }
            #pragma unroll
            for (int cf = 0; cf < 4; ++cf) {
                const int colb = bn * 64 + cf * 16 + g * 4;
                const f32x4 bv = *(const f32x4*)(bias + colb);
                if (EPI == 0) {
                    u16x4 o;
                    #pragma unroll
                    for (int e = 0; e < 4; ++e) o[e] = f2b(acc[cf][rf][e] + bv[e]);
                    *(u16x4*)((u16*)out + (size_t)row * N + colb) = o;
                } else if (EPI == 1) {
                    u16x4 o;
                    #pragma unroll
                    for (int e = 0; e < 4; ++e) o[e] = f2b(fast_gelu(acc[cf][rf][e] + bv[e]));
                    *(u16x4*)((u16*)out + (size_t)row * N + colb) = o;
                } else {
                    const f32x4 rv = *(const f32x4*)(resid + orow * N + colb);
                    f32x4 o;
                    #pragma unroll
                    for (int e = 0; e < 4; ++e) o[e] = rv[e] + acc[cf][rf][e] + bv[e];
                    *(f32x4*)((float*)out + orow * N + colb) = o;
                }
            }
        }
        FENCE();
    }
#undef STAGE
}

// ======== general-K 128x128 GEMM (MLP2): 4-buf, depth-2, 1 barrier/iter ====
__global__ __launch_bounds__(256)
void gemm_k4(const u16* __restrict__ A, const u16* __restrict__ Bt,
             const float* __restrict__ bias, float* __restrict__ out,
             const float* __restrict__ resid, int M, int N, int K)
{
    __shared__ u16 As[4][128][32];
    __shared__ u16 Bs[4][128][32];
    const int tid = threadIdx.x, lane = tid & 63, wv = tid >> 6;
    const int g = lane >> 4, r = lane & 15;
    const int wr = wv >> 1, wc = wv & 1;
    const int nwg = gridDim.x * gridDim.y;
    const int lid = blockIdx.y * gridDim.x + blockIdx.x;
    const int qq = nwg >> 3, r8 = nwg & 7;
    const int xcd = lid & 7, pos = lid >> 3;
    const int nid = (xcd < r8 ? xcd * (qq + 1) : r8 * (qq + 1) + (xcd - r8) * qq) + pos;
    const int bm = nid / gridDim.x, bn = nid % gridDim.x;
    f32x4 acc[4][4] = {};
    const int arow = wv * 16 + (lane >> 2);
    const int scol = (((lane & 3) ^ ((lane >> 2) & 3) ^ ((lane >> 4) & 1)) * 8);
    const u16* gA = A + (size_t)(bm * 128 + arow) * K + scol;
    const u16* gB = Bt + (size_t)(bn * 128 + arow) * K + scol;
    const int nk = K >> 5;
    const int rc = (g ^ (r & 3) ^ ((r >> 2) & 1)) * 8;

#define STAGE(t) do { \
        u16* a_ = &As[(t) & 3][0][0]; u16* b_ = &Bs[(t) & 3][0][0]; \
        GLOAD_LDS16(gA + (size_t)(t) * 32,                    a_ + wv * 512); \
        GLOAD_LDS16(gA + (size_t)(t) * 32 + (size_t)64 * K,   a_ + 2048 + wv * 512); \
        GLOAD_LDS16(gB + (size_t)(t) * 32,                    b_ + wv * 512); \
        GLOAD_LDS16(gB + (size_t)(t) * 32 + (size_t)64 * K,   b_ + 2048 + wv * 512); \
    } while (0)

    STAGE(0);
    STAGE(1);
    for (int kt = 0; kt < nk; ++kt) {
        const int cur = kt & 3;
        if (kt + 2 < nk) {
            STAGE(kt + 2);
            asm volatile("s_waitcnt vmcnt(8)" ::: "memory");
        } else if (kt + 1 < nk) {
            asm volatile("s_waitcnt vmcnt(4)" ::: "memory");
        } else {
            asm volatile("s_waitcnt vmcnt(0)" ::: "memory");
        }
        __builtin_amdgcn_s_barrier();
        FENCE();
        bf16x8 af[4], bf[4];
        #pragma unroll
        for (int i = 0; i < 4; ++i)
            af[i] = *(const bf16x8*)(&As[cur][wr * 64 + i * 16 + r][rc]);
        #pragma unroll
        for (int j = 0; j < 4; ++j)
            bf[j] = *(const bf16x8*)(&Bs[cur][wc * 64 + j * 16 + r][rc]);
        __builtin_amdgcn_s_setprio(1);
        #pragma unroll
        for (int j = 0; j < 4; ++j)
            #pragma unroll
            for (int i = 0; i < 4; ++i)
                acc[j][i] = __builtin_amdgcn_mfma_f32_16x16x32_bf16(bf[j], af[i], acc[j][i], 0, 0, 0);
        __builtin_amdgcn_s_setprio(0);
        asm volatile("s_waitcnt lgkmcnt(0)" ::: "memory");
        __builtin_amdgcn_sched_barrier(0);
    }
#undef STAGE

    #pragma unroll
    for (int i = 0; i < 4; ++i) {
        const int row = bm * 128 + wr * 64 + i * 16 + r;
        #pragma unroll
        for (int j = 0; j < 4; ++j) {
            const int colb = bn * 128 + wc * 64 + j * 16 + g * 4;
            const f32x4 bv = *(const f32x4*)(bias + colb);
            const f32x4 rv = *(const f32x4*)(resid + (size_t)row * N + colb);
            f32x4 o;
            #pragma unroll
            for (int e = 0; e < 4; ++e) o[e] = rv[e] + acc[j][i][e] + bv[e];
            *(f32x4*)(out + (size_t)row * N + colb) = o;
        }
    }
}

// ---------------- MFMA attention: one block per window, wave = 2 heads -----
template<int SHIFTED>
__global__ __launch_bounds__(256)
void attn_mfma(const u16* __restrict__ qkv, const float* __restrict__ bmT,
               u16* __restrict__ out)
{
    __shared__ u16 pbuf[4][64 * 72];
    __shared__ u16 vbuf[4][32 * 72];
    const int tid = threadIdx.x, lane = tid & 63, wv = tid >> 6;
    const int g = lane >> 4, r = lane & 15;
    const int win = blockIdx.x;
    u16* P  = pbuf[wv];
    u16* Vt = vbuf[wv];
    const u16* base = qkv + (size_t)win * 64 * 768;
    int cls = 0;
    if (SHIFTED) {
        int wib = win & 63;
        cls = (((wib >> 3) == 7) ? 2 : 0) + (((wib & 7) == 7) ? 1 : 0);
    }
    const float sc = 0.17677669529663687f * 1.4426950408889634f;

    for (int hh = 0; hh < 2; ++hh) {
        const int h = wv * 2 + hh;
        const float* bmh = bmT + ((size_t)cls * 8 + h) * 4096;
        bf16x8 kf[4], qf[4];
        #pragma unroll
        for (int i = 0; i < 4; ++i) {
            kf[i] = *(const bf16x8*)(base + (size_t)(i * 16 + r) * 768 + 256 + h * 32 + g * 8);
            qf[i] = *(const bf16x8*)(base + (size_t)(i * 16 + r) * 768 +       h * 32 + g * 8);
        }
        #pragma unroll
        for (int d0 = 0; d0 < 32; d0 += 8) {
            u16x8 vv = *(const u16x8*)(base + (size_t)lane * 768 + 512 + h * 32 + d0);
            #pragma unroll
            for (int e = 0; e < 8; ++e) Vt[(d0 + e) * 72 + lane] = vv[e];
        }
        f32x4 acc[4][4] = {};
        #pragma unroll
        for (int i = 0; i < 4; ++i)
            #pragma unroll
            for (int j = 0; j < 4; ++j)
                acc[i][j] = __builtin_amdgcn_mfma_f32_16x16x32_bf16(kf[i], qf[j], acc[i][j], 0, 0, 0);
        #pragma unroll
        for (int i = 0; i < 4; ++i) {
            const int kb = (i * 16 + g * 4) * 64;
            #pragma unroll
            for (int j = 0; j < 4; ++j) {
                const int qq = j * 16 + r;
                #pragma unroll
                for (int rr = 0; rr < 4; ++rr)
                    acc[i][j][rr] = acc[i][j][rr] * sc + bmh[kb + rr * 64 + qq];
            }
        }
        float inv_[4];
        #pragma unroll
        for (int j = 0; j < 4; ++j) {
            float m = acc[0][j][0];
            #pragma unroll
            for (int i = 0; i < 4; ++i)
                #pragma unroll
                for (int rr = 0; rr < 4; ++rr) m = fmaxf(m, acc[i][j][rr]);
            m = fmaxf(m, __shfl_xor(m, 16));
            m = fmaxf(m, __shfl_xor(m, 32));
            float s = 0.f;
            #pragma unroll
            for (int i = 0; i < 4; ++i)
                #pragma unroll
                for (int rr = 0; rr < 4; ++rr) {
                    float p = exp2f(acc[i][j][rr] - m);
                    acc[i][j][rr] = p; s += p;
                }
            s += __shfl_xor(s, 16);
            s += __shfl_xor(s, 32);
            inv_[j] = 1.f / s;
        }
        #pragma unroll
        for (int j = 0; j < 4; ++j) {
            const float iv = inv_[j];
            #pragma unroll
            for (int i = 0; i < 4; ++i) {
                u16x4 w;
                #pragma unroll
                for (int rr = 0; rr < 4; ++rr) w[rr] = f2b(acc[i][j][rr] * iv);
                *(u16x4*)(P + (j * 16 + r) * 72 + i * 16 + g * 4) = w;
            }
        }
        f32x4 o[2][4] = {};
        #pragma unroll
        for (int ks = 0; ks < 2; ++ks) {
            bf16x8 pa[4], vb[2];
            #pragma unroll
            for (int i = 0; i < 4; ++i)
                pa[i] = *(const bf16x8*)(P + (i * 16 + r) * 72 + ks * 32 + g * 8);
            #pragma unroll
            for (int j = 0; j < 2; ++j)
                vb[j] = *(const bf16x8*)(Vt + (j * 16 + r) * 72 + ks * 32 + g * 8);
            #pragma unroll
            for (int j = 0; j < 2; ++j)
                #pragma unroll
                for (int i = 0; i < 4; ++i)
                    o[j][i] = __builtin_amdgcn_mfma_f32_16x16x32_bf16(vb[j], pa[i], o[j][i], 0, 0, 0);
        }
        u16* op = out + (size_t)win * 64 * 256 + h * 32;
        #pragma unroll
        for (int i = 0; i < 4; ++i) {
            const int qrow = i * 16 + r;
            #pragma unroll
            for (int j = 0; j < 2; ++j) {
                u16x4 w;
                #pragma unroll
                for (int rr = 0; rr < 4; ++rr) w[rr] = f2b(o[j][i][rr]);
                *(u16x4*)(op + (size_t)qrow * 256 + j * 16 + g * 4) = w;
            }
        }
    }
}

// ---------------------------------------------------------------------------
extern "C" void kernel_launch(void* const* d_in, const int* in_sizes, int n_in,
                              void* d_out, int out_size, void* d_ws, size_t ws_size,
                              hipStream_t stream)
{
    (void)in_sizes; (void)n_in; (void)out_size; (void)ws_size;
    const float* x = (const float*)d_in[0];
    char* ws = (char*)d_ws;
    size_t off = 0;
    auto alloc = [&](size_t bytes) { void* p = ws + off; off += (bytes + 255) & ~(size_t)255; return p; };

    u16 *wtq[2], *wto[2], *wt1[2], *wt2[2];
    float* bmT[2];
    for (int i = 0; i < 2; ++i) {
        wtq[i] = (u16*)alloc((size_t)768 * 256 * 2);
        wto[i] = (u16*)alloc((size_t)256 * 256 * 2);
        wt1[i] = (u16*)alloc((size_t)1024 * 256 * 2);
        wt2[i] = (u16*)alloc((size_t)256 * 1024 * 2);
        bmT[i] = (float*)alloc((size_t)4 * 8 * 64 * 64 * 4);
    }
    u16*  xw  = (u16*)alloc((size_t)65536 * 256 * 2);    // LN out / attn out
    u16*  big = (u16*)alloc((size_t)65536 * 1024 * 2);   // qkv / mlp hidden
    float* x1 = (float*)alloc((size_t)65536 * 256 * 4);  // post-attn residual stream
    float* outp = (float*)d_out;

    for (int blk = 0; blk < 2; ++blk) {
        const float* const* P = (const float* const*)(d_in + 1 + blk * 15);
        transpose_w<<<dim3(768 / 32, 256 / 32), 256, 0, stream>>>(P[2], wtq[blk], 256, 768);
        transpose_w<<<dim3(256 / 32, 256 / 32), 256, 0, stream>>>(P[5], wto[blk], 256, 256);
        transpose_w<<<dim3(1024 / 32, 256 / 32), 256, 0, stream>>>(P[11], wt1[blk], 256, 1024);
        transpose_w<<<dim3(256 / 32, 1024 / 32), 256, 0, stream>>>(P[13], wt2[blk], 1024, 256);
        build_bias<<<512, 256, 0, stream>>>(P[4], bmT[blk]);
    }

    for (int blk = 0; blk < 2; ++blk) {
        const float* const* P = (const float* const*)(d_in + 1 + blk * 15);
        const int sh = blk ? 4 : 0;
        const float* xin = blk ? outp : x;

        ln_win_kernel<<<16384, 256, 0, stream>>>(xin, P[0], P[1], xw, sh);
        areg_gemm<0><<<512, 256, 0, stream>>>(xw, wtq[blk], P[3], big, nullptr, 768, 0);
        if (blk) attn_mfma<1><<<1024, 256, 0, stream>>>(big, bmT[blk], xw);
        else     attn_mfma<0><<<1024, 256, 0, stream>>>(big, bmT[blk], xw);
        areg_gemm<2><<<512, 256, 0, stream>>>(xw, wto[blk], P[6], x1, xin, 256, sh);
        ln2_kernel<<<16384, 256, 0, stream>>>(x1, P[7], P[8], P[9], P[10], xw);
        areg_gemm<1><<<512, 256, 0, stream>>>(xw, wt1[blk], P[12], big, nullptr, 1024, 0);
        gemm_k4<<<dim3(2, 512), 256, 0, stream>>>(big, wt2[blk], P[14], outp, x1, 65536, 256, 1024);
    }
}